// Round 3
// baseline (179.242 us; speedup 1.0000x reference)
//
#include <hip/hip_runtime.h>
#include <math.h>

#define SB 8
#define SS 2048
#define SH 768
#define ALPHA 0.5f

typedef __fp16 f16x8 __attribute__((ext_vector_type(8)));
typedef float f32x4 __attribute__((ext_vector_type(4)));

__device__ __forceinline__ float dot4(float4 a, float4 b) {
  return a.x*b.x + a.y*b.y + a.z*b.z + a.w*b.w;
}
__device__ __forceinline__ unsigned int pk2(float a, float b) {
  return __builtin_bit_cast(unsigned int, __builtin_amdgcn_cvt_pkrtz(a, b));
}

// ws layout: Khs [SB*SS*SH] f16 (k_hat * km baked)  ~24 MB
//            | ksum [SB*SH] f32 | Nk[8] qsum[8] acc[8] cnt[8]

// K prep: per-row norm -> Khs (f16, km/||k|| baked in), ksum = sum of rows,
// Nk = sum(km), qsum = sum(qm).  grid (64, SB), block 256 = 4 waves x 8 rows.
__global__ __launch_bounds__(256) void kprep_kernel(
    const float* __restrict__ K, const float* __restrict__ km,
    const float* __restrict__ qm,
    __fp16* __restrict__ Khs, float* __restrict__ ksum,
    float* __restrict__ Nk, float* __restrict__ qsum) {
  __shared__ float4 red[4][3][64];     // 12 KB
  int b = blockIdx.y, jc = blockIdx.x, t = threadIdx.x;
  int w = t >> 6, lane = t & 63;
  int j0 = jc * 32;
  float4 acc0 = {0,0,0,0}, acc1 = {0,0,0,0}, acc2 = {0,0,0,0};
  for (int jj = 0; jj < 8; ++jj) {
    int j = j0 + 8 * w + jj;
    const float4* rp = (const float4*)(K + ((size_t)b * SS + j) * SH);
    float4 a = rp[lane], b4 = rp[lane + 64], c4 = rp[lane + 128];
    float ssv = dot4(a, a) + dot4(b4, b4) + dot4(c4, c4);
    #pragma unroll
    for (int m = 1; m < 64; m <<= 1) ssv += __shfl_xor(ssv, m, 64);
    float kwj = km[b * SS + j] / fmaxf(sqrtf(ssv), 1e-12f);
    uint2* kr = (uint2*)(Khs + ((size_t)b * SS + j) * SH);
    kr[lane]       = make_uint2(pk2(a.x*kwj,  a.y*kwj),  pk2(a.z*kwj,  a.w*kwj));
    kr[lane + 64]  = make_uint2(pk2(b4.x*kwj, b4.y*kwj), pk2(b4.z*kwj, b4.w*kwj));
    kr[lane + 128] = make_uint2(pk2(c4.x*kwj, c4.y*kwj), pk2(c4.z*kwj, c4.w*kwj));
    acc0.x += a.x*kwj;  acc0.y += a.y*kwj;  acc0.z += a.z*kwj;  acc0.w += a.w*kwj;
    acc1.x += b4.x*kwj; acc1.y += b4.y*kwj; acc1.z += b4.z*kwj; acc1.w += b4.w*kwj;
    acc2.x += c4.x*kwj; acc2.y += c4.y*kwj; acc2.z += c4.z*kwj; acc2.w += c4.w*kwj;
  }
  red[w][0][lane] = acc0; red[w][1][lane] = acc1; red[w][2][lane] = acc2;
  __syncthreads();
  if (t < 192) {
    int s = t >> 6, l = t & 63;
    float4 r0 = red[0][s][l], r1 = red[1][s][l], r2 = red[2][s][l], r3 = red[3][s][l];
    float* kp = ksum + b * SH + (s * 64 + l) * 4;
    atomicAdd(kp + 0, r0.x+r1.x+r2.x+r3.x);
    atomicAdd(kp + 1, r0.y+r1.y+r2.y+r3.y);
    atomicAdd(kp + 2, r0.z+r1.z+r2.z+r3.z);
    atomicAdd(kp + 3, r0.w+r1.w+r2.w+r3.w);
  }
  if (t < 32) {
    float pkm = km[b * SS + j0 + t];
    float pqm = qm[b * SS + j0 + t];
    #pragma unroll
    for (int m = 1; m < 32; m <<= 1) {
      pkm += __shfl_xor(pkm, m, 64);
      pqm += __shfl_xor(pqm, m, 64);
    }
    if (t == 0) { atomicAdd(&Nk[b], pkm); atomicAdd(&qsum[b], pqm); }
  }
}

// Band kernel, barrier-free: 4 independent waves per block, each owns 16
// q-rows with full K=768 in registers and walks its 80-col band as 5x16-col
// tiles, loading B fragments straight from global (L2-resident Khs).
// Software-pipelined 12-deep B double-buffer; no LDS staging at all.
__global__ __launch_bounds__(256, 1) void band_kernel(
    const float* __restrict__ Q, const __fp16* __restrict__ Khs,
    const float* __restrict__ temp, const float* __restrict__ qm,
    const float* __restrict__ ksum, const float* __restrict__ Nkp,
    const float* __restrict__ qsum,
    float* __restrict__ acc, int* __restrict__ cnt, float* __restrict__ out) {
  __shared__ float tab_s[64];
  int tid = threadIdx.x;
  int w = tid >> 6, lane = tid & 63;
  int l15 = lane & 15, quad = lane >> 4;
  int blk = blockIdx.x;
  int work = (blk & 7) * 32 + (blk >> 3);  // grid 256: batch b -> XCD b
  int b = work >> 5;
  int i0 = (work & 31) * 64;
  int i0w = i0 + 16 * w;                   // this wave's 16 q-rows
  int qrow = i0w + l15;

  float qmv = qm[b * SS + qrow];
  float nk = Nkp[b];
  // benign same-value race: every wave writes the whole table, then waits on
  // its OWN lgkm count before reading -> no barrier needed.
  {
    float invt = 1.0f / temp[0];
    tab_s[lane] = __expf(-ALPHA * fabsf((float)(lane - 31))) * invt;
  }
  asm volatile("s_waitcnt lgkmcnt(0)" ::: "memory");

  // ---- prologue: full-row A-frags (f16 of raw q), ||q||^2, d0 = q.ksum
  const float* qp = Q + ((size_t)b * SS + qrow) * SH + quad * 8;
  const float* kp = ksum + (size_t)b * SH + quad * 8;
  f16x8 afr[24];
  float ss = 0.f, dd = 0.f;
  #pragma unroll
  for (int s = 0; s < 24; ++s) {
    float4 x0 = *(const float4*)(qp + 32 * s);
    float4 x1 = *(const float4*)(qp + 32 * s + 4);
    float4 k0 = *(const float4*)(kp + 32 * s);
    float4 k1 = *(const float4*)(kp + 32 * s + 4);
    ss += dot4(x0, x0) + dot4(x1, x1);
    dd += dot4(x0, k0) + dot4(x1, k1);
    uint4 u = make_uint4(pk2(x0.x, x0.y), pk2(x0.z, x0.w),
                         pk2(x1.x, x1.y), pk2(x1.z, x1.w));
    afr[s] = __builtin_bit_cast(f16x8, u);
  }
  ss += __shfl_xor(ss, 16, 64); ss += __shfl_xor(ss, 32, 64);
  dd += __shfl_xor(dd, 16, 64); dd += __shfl_xor(dd, 32, 64);
  float qw = qmv / fmaxf(sqrtf(ss), 1e-12f);
  float qwsr[4], d0r[4];
  #pragma unroll
  for (int r = 0; r < 4; ++r) {            // values for epilogue rows quad*4+r
    qwsr[r] = __shfl(qw, quad * 4 + r, 64);
    d0r[r]  = __shfl(dd, quad * 4 + r, 64);
  }

  // ---- banded S = A.B over 5 j-tiles of 16, direct-global B, 12-deep pipe
  const __fp16* KbH = Khs + (size_t)b * SS * SH;
  f16x8 bqA[12], bqB[12];
  {
    int j = i0w - 32 + l15;
    int jc = min(max(j, 0), SS - 1);
    const __fp16* rp = KbH + (size_t)jc * SH + quad * 8;
    #pragma unroll
    for (int u = 0; u < 12; ++u) bqA[u] = *(const f16x8*)(rp + u * 32);
  }
  float an[4] = {0,0,0,0}, ad[4] = {0,0,0,0};
  f32x4 da = {0,0,0,0}, db = {0,0,0,0};
  #pragma unroll
  for (int fi = 0; fi < 10; ++fi) {        // fi = t*2 + g, groups of 12 k-slices
    const int t = fi >> 1, g = fi & 1;
    if (fi < 9) {                          // prefetch next group, other buffer
      const int tn = (fi + 1) >> 1, gn = (fi + 1) & 1;
      int j = i0w - 32 + 16 * tn + l15;
      int jc = min(max(j, 0), SS - 1);
      const __fp16* rp = KbH + (size_t)jc * SH + gn * 384 + quad * 8;
      #pragma unroll
      for (int u = 0; u < 12; ++u) {
        f16x8 v = *(const f16x8*)(rp + u * 32);
        if (fi & 1) bqA[u] = v; else bqB[u] = v;
      }
    }
    #pragma unroll
    for (int u = 0; u < 12; ++u) {
      f16x8 bv = (fi & 1) ? bqB[u] : bqA[u];
      if (u & 1) db = __builtin_amdgcn_mfma_f32_16x16x32_f16(afr[g*12+u], bv, db, 0, 0, 0);
      else       da = __builtin_amdgcn_mfma_f32_16x16x32_f16(afr[g*12+u], bv, da, 0, 0, 0);
    }
    if (g) {                               // tile t complete -> epilogue
      f32x4 ds = da + db;
      int j = i0w - 32 + 16 * t + l15;
      float vmask = ((unsigned)j < SS) ? 1.0f : 0.0f;
      int idxb = j - i0w + 31;
      #pragma unroll
      for (int reg = 0; reg < 4; ++reg) {
        float sv = ds[reg] * qwsr[reg];    // kw baked in Khs
        int idx = min(max(idxb - quad * 4 - reg, 0), 63);
        float ev = (__expf(sv * tab_s[idx]) - 1.0f) * vmask;
        an[reg] += ev * sv;
        ad[reg] += ev;
      }
      da = (f32x4){0,0,0,0}; db = (f32x4){0,0,0,0};
    }
  }

  // fold k-cols (l15) per row, score, wave total -> atomic
  float tot = 0.f;
  #pragma unroll
  for (int reg = 0; reg < 4; ++reg) {
    float a = an[reg], e = ad[reg];
    a += __shfl_xor(a, 1, 64); a += __shfl_xor(a, 2, 64);
    a += __shfl_xor(a, 4, 64); a += __shfl_xor(a, 8, 64);
    e += __shfl_xor(e, 1, 64); e += __shfl_xor(e, 2, 64);
    e += __shfl_xor(e, 4, 64); e += __shfl_xor(e, 8, 64);
    tot += (qwsr[reg] * d0r[reg] + a) / (nk + e);
  }
  tot += __shfl_xor(tot, 16, 64);          // sum across the 4 quads
  tot += __shfl_xor(tot, 32, 64);
  if (lane == 0) {
    atomicAdd(&acc[b], tot);
    __threadfence();
    if (atomicAdd(&cnt[b], 1) == 127) {    // 32 blocks x 4 waves per batch
      float a2 = atomicAdd(&acc[b], 0.0f);
      out[b] = a2 / fmaxf(qsum[b], 1.0f);
    }
  }
}

extern "C" void kernel_launch(void* const* d_in, const int* in_sizes, int n_in,
                              void* d_out, int out_size, void* d_ws, size_t ws_size,
                              hipStream_t stream) {
  const float* Q    = (const float*)d_in[0];
  const float* K    = (const float*)d_in[1];
  const float* qm   = (const float*)d_in[2];
  const float* km   = (const float*)d_in[3];
  const float* temp = (const float*)d_in[4];
  float* outp = (float*)d_out;

  const size_t KHS_BYTES = (size_t)SB * SS * SH * 2;  // ~24 MB (proven to fit in ws)
  __fp16* Khs = (__fp16*)d_ws;
  float* ksum = (float*)((char*)d_ws + KHS_BYTES);
  float* Nk   = ksum + SB * SH;
  float* qsum = Nk + 8;
  float* accb = qsum + 8;
  int*   cnt  = (int*)(accb + 8);

  (void)hipMemsetAsync(ksum, 0, (SB * SH + 32) * sizeof(float), stream);

  kprep_kernel<<<dim3(64, SB), 256, 0, stream>>>(K, km, qm, Khs, ksum, Nk, qsum);
  band_kernel<<<SB * (SS / 64), 256, 0, stream>>>(Q, Khs, temp, qm, ksum, Nk,
                                                  qsum, accb, cnt, outp);
}

// Round 4
// 169.637 us; speedup vs baseline: 1.0566x; 1.0566x over previous
//
#include <hip/hip_runtime.h>
#include <math.h>

#define SB 8
#define SS 2048
#define SH 768
#define ALPHA 0.5f

typedef __fp16 f16x8 __attribute__((ext_vector_type(8)));
typedef float f32x4 __attribute__((ext_vector_type(4)));

__device__ __forceinline__ float dot4(float4 a, float4 b) {
  return a.x*b.x + a.y*b.y + a.z*b.z + a.w*b.w;
}
__device__ __forceinline__ unsigned int pk2(float a, float b) {
  return __builtin_bit_cast(unsigned int, __builtin_amdgcn_cvt_pkrtz(a, b));
}

// pinned-register global load with literal immediate offset (bytes)
#define GLOAD(d, p, imm) \
  asm volatile("global_load_dwordx4 %0, %1, off offset:" #imm \
               : "=v"(d) : "v"(p) : "memory")
// K-slices 0..11 (k = 0..383): byte offsets 0..704
#define ISSUE_LO(B, P) do { \
  GLOAD(B[0],P,0);    GLOAD(B[1],P,64);   GLOAD(B[2],P,128);  \
  GLOAD(B[3],P,192);  GLOAD(B[4],P,256);  GLOAD(B[5],P,320);  \
  GLOAD(B[6],P,384);  GLOAD(B[7],P,448);  GLOAD(B[8],P,512);  \
  GLOAD(B[9],P,576);  GLOAD(B[10],P,640); GLOAD(B[11],P,704); } while (0)
// K-slices 12..23 (k = 384..767): byte offsets 768..1472
#define ISSUE_HI(B, P) do { \
  GLOAD(B[0],P,768);  GLOAD(B[1],P,832);  GLOAD(B[2],P,896);  \
  GLOAD(B[3],P,960);  GLOAD(B[4],P,1024); GLOAD(B[5],P,1088); \
  GLOAD(B[6],P,1152); GLOAD(B[7],P,1216); GLOAD(B[8],P,1280); \
  GLOAD(B[9],P,1344); GLOAD(B[10],P,1408); GLOAD(B[11],P,1472); } while (0)
#define WAITV(n) asm volatile("s_waitcnt vmcnt(" #n ")" ::: "memory")
#define SB0() __builtin_amdgcn_sched_barrier(0)

__device__ __forceinline__ void mfma12(const f16x8* a, const f16x8* B,
                                       f32x4& da, f32x4& db) {
  #pragma unroll
  for (int u = 0; u < 12; ++u) {
    if (u & 1) db = __builtin_amdgcn_mfma_f32_16x16x32_f16(a[u], B[u], db, 0, 0, 0);
    else       da = __builtin_amdgcn_mfma_f32_16x16x32_f16(a[u], B[u], da, 0, 0, 0);
  }
}

// ws layout: Khs [SB*SS*SH] f16 (k_hat * km baked)  ~24 MB
//            | ksum [SB*SH] f32 | Nk[8] qsum[8] acc[8] cnt[8]

// K prep (unchanged): per-row norm -> Khs f16, ksum, Nk, qsum.
__global__ __launch_bounds__(256) void kprep_kernel(
    const float* __restrict__ K, const float* __restrict__ km,
    const float* __restrict__ qm,
    __fp16* __restrict__ Khs, float* __restrict__ ksum,
    float* __restrict__ Nk, float* __restrict__ qsum) {
  __shared__ float4 red[4][3][64];     // 12 KB
  int b = blockIdx.y, jc = blockIdx.x, t = threadIdx.x;
  int w = t >> 6, lane = t & 63;
  int j0 = jc * 32;
  float4 acc0 = {0,0,0,0}, acc1 = {0,0,0,0}, acc2 = {0,0,0,0};
  for (int jj = 0; jj < 8; ++jj) {
    int j = j0 + 8 * w + jj;
    const float4* rp = (const float4*)(K + ((size_t)b * SS + j) * SH);
    float4 a = rp[lane], b4 = rp[lane + 64], c4 = rp[lane + 128];
    float ssv = dot4(a, a) + dot4(b4, b4) + dot4(c4, c4);
    #pragma unroll
    for (int m = 1; m < 64; m <<= 1) ssv += __shfl_xor(ssv, m, 64);
    float kwj = km[b * SS + j] / fmaxf(sqrtf(ssv), 1e-12f);
    uint2* kr = (uint2*)(Khs + ((size_t)b * SS + j) * SH);
    kr[lane]       = make_uint2(pk2(a.x*kwj,  a.y*kwj),  pk2(a.z*kwj,  a.w*kwj));
    kr[lane + 64]  = make_uint2(pk2(b4.x*kwj, b4.y*kwj), pk2(b4.z*kwj, b4.w*kwj));
    kr[lane + 128] = make_uint2(pk2(c4.x*kwj, c4.y*kwj), pk2(c4.z*kwj, c4.w*kwj));
    acc0.x += a.x*kwj;  acc0.y += a.y*kwj;  acc0.z += a.z*kwj;  acc0.w += a.w*kwj;
    acc1.x += b4.x*kwj; acc1.y += b4.y*kwj; acc1.z += b4.z*kwj; acc1.w += b4.w*kwj;
    acc2.x += c4.x*kwj; acc2.y += c4.y*kwj; acc2.z += c4.z*kwj; acc2.w += c4.w*kwj;
  }
  red[w][0][lane] = acc0; red[w][1][lane] = acc1; red[w][2][lane] = acc2;
  __syncthreads();
  if (t < 192) {
    int s = t >> 6, l = t & 63;
    float4 r0 = red[0][s][l], r1 = red[1][s][l], r2 = red[2][s][l], r3 = red[3][s][l];
    float* kp = ksum + b * SH + (s * 64 + l) * 4;
    atomicAdd(kp + 0, r0.x+r1.x+r2.x+r3.x);
    atomicAdd(kp + 1, r0.y+r1.y+r2.y+r3.y);
    atomicAdd(kp + 2, r0.z+r1.z+r2.z+r3.z);
    atomicAdd(kp + 3, r0.w+r1.w+r2.w+r3.w);
  }
  if (t < 32) {
    float pkm = km[b * SS + j0 + t];
    float pqm = qm[b * SS + j0 + t];
    #pragma unroll
    for (int m = 1; m < 32; m <<= 1) {
      pkm += __shfl_xor(pkm, m, 64);
      pqm += __shfl_xor(pqm, m, 64);
    }
    if (t == 0) { atomicAdd(&Nk[b], pkm); atomicAdd(&qsum[b], pqm); }
  }
}

// Band kernel: 512 blocks (64/batch, batch->XCD), block = 32 q-rows.
// 4 waves = 2 row-groups x 2 col-halves; half 0 owns j-tiles {0,1,2},
// half 1 owns {3,4}. B fragments loaded direct-from-global via inline-asm
// pinned registers, hand-counted vmcnt double-buffer (24 loads in flight).
__global__ __launch_bounds__(256, 2) void band_kernel(
    const float* __restrict__ Q, const __fp16* __restrict__ Khs,
    const float* __restrict__ temp, const float* __restrict__ qm,
    const float* __restrict__ ksum, const float* __restrict__ Nkp,
    const float* __restrict__ qsum,
    float* __restrict__ acc, int* __restrict__ cnt, float* __restrict__ out) {
  __shared__ float tab_s[64];
  __shared__ float anS[2][2][16], adS[2][2][16];
  __shared__ float qwS[2][16], d0S[2][16];
  int tid = threadIdx.x;
  int w = tid >> 6, lane = tid & 63;
  int l15 = lane & 15, quad = lane >> 4;
  int rg = w >> 1, h = w & 1;
  int blk = blockIdx.x;
  int work = (blk & 7) * 64 + (blk >> 3);  // batch b -> XCD b (64 blocks each)
  int b = work >> 6;
  int i0 = (work & 63) * 32;
  int i0w = i0 + 16 * rg;                  // this wave's 16 q-rows
  int qrow = i0w + l15;
  int jbase = i0w - 32;                    // band cols [jbase, jbase+79]

  float qmv = qm[b * SS + qrow];
  float nk = Nkp[b];
  {                                        // benign same-value race
    float invt = 1.0f / temp[0];
    tab_s[lane] = __expf(-ALPHA * fabsf((float)(lane - 31))) * invt;
  }
  asm volatile("s_waitcnt lgkmcnt(0)" ::: "memory");

  // ---- prologue: full-row A-frags (f16 of raw q), ||q||^2, d0 = q.ksum
  const float* qp = Q + ((size_t)b * SS + qrow) * SH + quad * 8;
  const float* kp = ksum + (size_t)b * SH + quad * 8;
  f16x8 afr[24];
  float ss = 0.f, dd = 0.f;
  #pragma unroll
  for (int s = 0; s < 24; ++s) {
    float4 x0 = *(const float4*)(qp + 32 * s);
    float4 x1 = *(const float4*)(qp + 32 * s + 4);
    float4 k0 = *(const float4*)(kp + 32 * s);
    float4 k1 = *(const float4*)(kp + 32 * s + 4);
    ss += dot4(x0, x0) + dot4(x1, x1);
    dd += dot4(x0, k0) + dot4(x1, k1);
    uint4 u = make_uint4(pk2(x0.x, x0.y), pk2(x0.z, x0.w),
                         pk2(x1.x, x1.y), pk2(x1.z, x1.w));
    afr[s] = __builtin_bit_cast(f16x8, u);
  }
  ss += __shfl_xor(ss, 16, 64); ss += __shfl_xor(ss, 32, 64);
  dd += __shfl_xor(dd, 16, 64); dd += __shfl_xor(dd, 32, 64);
  float qw = qmv / fmaxf(sqrtf(ss), 1e-12f);
  float qwsr[4], d0r[4];
  #pragma unroll
  for (int r = 0; r < 4; ++r) {            // values for epilogue rows quad*4+r
    qwsr[r] = __shfl(qw, quad * 4 + r, 64);
    d0r[r]  = __shfl(dd, quad * 4 + r, 64);
  }

  const __fp16* KbH = Khs + (size_t)b * SS * SH;
  auto tp = [&](int t) {                   // per-tile lane base pointer
    int jc = min(max(jbase + 16 * t + l15, 0), SS - 1);
    return KbH + (size_t)jc * SH + quad * 8;
  };

  float an[4] = {0,0,0,0}, ad[4] = {0,0,0,0};
  f32x4 da = {0,0,0,0}, db = {0,0,0,0};
  auto epi = [&](int t) {                  // tile complete -> softmax terms
    f32x4 ds = da + db;
    int j = jbase + 16 * t + l15;
    float vmask = ((unsigned)j < SS) ? 1.0f : 0.0f;
    int idxb = 16 * t + l15 - 1;           // = j - i0w + 31
    #pragma unroll
    for (int reg = 0; reg < 4; ++reg) {
      float sv = ds[reg] * qwsr[reg];      // kw baked into Khs
      int idx = min(max(idxb - quad * 4 - reg, 0), 63);
      float ev = (__expf(sv * tab_s[idx]) - 1.0f) * vmask;
      an[reg] += ev * sv;
      ad[reg] += ev;
    }
    da = (f32x4){0,0,0,0}; db = (f32x4){0,0,0,0};
  };

  f16x8 bqA[12], bqB[12];
  // drain: after this, every outstanding VMEM op is one of ours.
  WAITV(0);
  if (h == 0) {                            // tiles 0,1,2 (6 half-K groups)
    const __fp16* P0 = tp(0); const __fp16* P1 = tp(1); const __fp16* P2 = tp(2);
    ISSUE_LO(bqA, P0); ISSUE_HI(bqB, P0);          // 24 in flight
    WAITV(12); SB0(); mfma12(afr,      bqA, da, db);
    ISSUE_LO(bqA, P1);                             // 24
    WAITV(12); SB0(); mfma12(afr + 12, bqB, da, db); epi(0);
    ISSUE_HI(bqB, P1);                             // 24
    WAITV(12); SB0(); mfma12(afr,      bqA, da, db);
    ISSUE_LO(bqA, P2);                             // 24
    WAITV(12); SB0(); mfma12(afr + 12, bqB, da, db); epi(1);
    ISSUE_HI(bqB, P2);                             // 24
    WAITV(12); SB0(); mfma12(afr,      bqA, da, db);
    WAITV(0);  SB0(); mfma12(afr + 12, bqB, da, db); epi(2);
  } else {                                 // tiles 3,4 (4 half-K groups)
    const __fp16* P3 = tp(3); const __fp16* P4 = tp(4);
    ISSUE_LO(bqA, P3); ISSUE_HI(bqB, P3);          // 24
    WAITV(12); SB0(); mfma12(afr,      bqA, da, db);
    ISSUE_LO(bqA, P4);                             // 24
    WAITV(12); SB0(); mfma12(afr + 12, bqB, da, db); epi(3);
    ISSUE_HI(bqB, P4);                             // 24
    WAITV(12); SB0(); mfma12(afr,      bqA, da, db);
    WAITV(0);  SB0(); mfma12(afr + 12, bqB, da, db); epi(4);
  }

  // fold k-cols (l15) within wave, publish per-row half-partials to LDS
  #pragma unroll
  for (int reg = 0; reg < 4; ++reg) {
    float a = an[reg], e = ad[reg];
    a += __shfl_xor(a, 1, 64); a += __shfl_xor(a, 2, 64);
    a += __shfl_xor(a, 4, 64); a += __shfl_xor(a, 8, 64);
    e += __shfl_xor(e, 1, 64); e += __shfl_xor(e, 2, 64);
    e += __shfl_xor(e, 4, 64); e += __shfl_xor(e, 8, 64);
    if (l15 == 0) { anS[rg][h][quad * 4 + reg] = a; adS[rg][h][quad * 4 + reg] = e; }
  }
  if (h == 0 && lane < 16) { qwS[rg][lane] = qw; d0S[rg][lane] = dd; }
  __syncthreads();                         // all VMEM drained above -> safe
  if (tid < 32) {
    int rgc = tid >> 4, rr = tid & 15;
    float a = anS[rgc][0][rr] + anS[rgc][1][rr];
    float e = adS[rgc][0][rr] + adS[rgc][1][rr];
    float sc = (qwS[rgc][rr] * d0S[rgc][rr] + a) / (nk + e);
    sc += __shfl_xor(sc, 1, 64); sc += __shfl_xor(sc, 2, 64);
    sc += __shfl_xor(sc, 4, 64); sc += __shfl_xor(sc, 8, 64);
    sc += __shfl_xor(sc, 16, 64);
    if (tid == 0) {
      atomicAdd(&acc[b], sc);
      __threadfence();
      if (atomicAdd(&cnt[b], 1) == 63) {   // last of 64 blocks for batch b
        float a2 = atomicAdd(&acc[b], 0.0f);
        out[b] = a2 / fmaxf(qsum[b], 1.0f);
      }
    }
  }
}

extern "C" void kernel_launch(void* const* d_in, const int* in_sizes, int n_in,
                              void* d_out, int out_size, void* d_ws, size_t ws_size,
                              hipStream_t stream) {
  const float* Q    = (const float*)d_in[0];
  const float* K    = (const float*)d_in[1];
  const float* qm   = (const float*)d_in[2];
  const float* km   = (const float*)d_in[3];
  const float* temp = (const float*)d_in[4];
  float* outp = (float*)d_out;

  const size_t KHS_BYTES = (size_t)SB * SS * SH * 2;  // ~24 MB (fits ws, proven r2)
  __fp16* Khs = (__fp16*)d_ws;
  float* ksum = (float*)((char*)d_ws + KHS_BYTES);
  float* Nk   = ksum + SB * SH;
  float* qsum = Nk + 8;
  float* accb = qsum + 8;
  int*   cnt  = (int*)(accb + 8);

  (void)hipMemsetAsync(ksum, 0, (SB * SH + 32) * sizeof(float), stream);

  kprep_kernel<<<dim3(64, SB), 256, 0, stream>>>(K, km, qm, Khs, ksum, Nk, qsum);
  band_kernel<<<512, 256, 0, stream>>>(Q, Khs, temp, qm, ksum, Nk,
                                       qsum, accb, cnt, outp);
}